// Round 4
// baseline (1595.163 us; speedup 1.0000x reference)
//
#include <hip/hip_runtime.h>
#include <hip/hip_bf16.h>
#include <cstdint>
#include <cstddef>

typedef __bf16 bf16;
typedef __bf16 bf16x4 __attribute__((ext_vector_type(4)));
typedef __bf16 bf16x8 __attribute__((ext_vector_type(8)));
typedef float  f32x4  __attribute__((ext_vector_type(4)));

#define BATCH 16
#define NQ    576
#define MM    1024
#define HID   4096
#define HEADS 8
#define DH    128
#define ROWS  (BATCH*NQ)   // 9216

// ---- async global->LDS, 16B per lane --------------------------------------
typedef const unsigned int __attribute__((address_space(1)))* gas_ptr;
typedef unsigned int __attribute__((address_space(3)))* las_ptr;

__device__ __forceinline__ void async16(const bf16* g, bf16* l) {
  __builtin_amdgcn_global_load_lds((gas_ptr)g, (las_ptr)l, 16, 0, 0);
}

// ---- f32 -> bf16 streaming convert (n % 1024 == 0) ------------------------
__global__ __launch_bounds__(256) void cvt_kernel(
    const float* __restrict__ s, bf16* __restrict__ d)
{
  const int i = (blockIdx.x * 256 + threadIdx.x) * 4;
  f32x4 v = *(const f32x4*)(s + i);
  bf16x4 o;
#pragma unroll
  for (int j = 0; j < 4; ++j) o[j] = (bf16)v[j];
  *(bf16x4*)(d + i) = o;
}

enum { MODE_BIAS = 0, MODE_GB = 3 };

// ===========================================================================
// gemm_bt: C[M,N] = A[M,K] @ W[N,K]^T (+epilogue). 128x128 tile, BK=32,
// 4 waves, 4x4 MFMA 16x16x32. XCD-bijective block swizzle for L2 locality
// (requires gridDim.x*gridDim.y % 8 == 0 — true for all our grids).
// ===========================================================================
template <int MODE, typename OutT>
__global__ __launch_bounds__(256) void gemm_bt(
    const bf16* __restrict__ A, const bf16* __restrict__ W,
    const float* __restrict__ bias, OutT* __restrict__ C,
    const float* __restrict__ gates, int M, int N, int K)
{
  __shared__ bf16 As[128 * 32];
  __shared__ bf16 Bs[128 * 32];

  const int tid  = threadIdx.x;
  const int lane = tid & 63;
  const int w    = tid >> 6;
  const int wm   = (w & 1) * 64;
  const int wn   = (w >> 1) * 64;
  const int l15  = lane & 15;
  const int quad = lane >> 4;

  // XCD-bijective swizzle: consecutive remapped blocks land on the same XCD
  // and walk n fastest -> A-panel stays hot in that XCD's L2.
  const int gx  = gridDim.x;
  const int nwg = gx * gridDim.y;
  const int cpx = nwg >> 3;                      // nwg % 8 == 0
  int lin = blockIdx.y * gx + blockIdx.x;
  lin = (lin & 7) * cpx + (lin >> 3);
  const int m0 = (lin / gx) * 128;
  const int n0 = (lin % gx) * 128;

  f32x4 acc[4][4] = {};

  int ar0 = m0 + (tid >> 2);      if (ar0 > M - 1) ar0 = M - 1;
  int ar1 = m0 + 64 + (tid >> 2); if (ar1 > M - 1) ar1 = M - 1;
  const int kc = (tid & 3) * 8;
  const bf16* ap0 = A + (size_t)ar0 * K + kc;
  const bf16* ap1 = A + (size_t)ar1 * K + kc;
  const bf16* bp0 = W + (size_t)(n0 + (tid >> 2)) * K + kc;
  const bf16* bp1 = W + (size_t)(n0 + 64 + (tid >> 2)) * K + kc;
  bf16* lA0 = As + tid * 8;
  bf16* lA1 = As + 2048 + tid * 8;
  bf16* lB0 = Bs + tid * 8;
  bf16* lB1 = Bs + 2048 + tid * 8;

  const int ko = quad * 8;

  for (int kt = 0; kt < K; kt += 32) {
    async16(ap0 + kt, lA0);
    async16(ap1 + kt, lA1);
    async16(bp0 + kt, lB0);
    async16(bp1 + kt, lB1);
    __syncthreads();

    bf16x8 af[4], bfr[4];
#pragma unroll
    for (int i = 0; i < 4; ++i)
      af[i] = *(const bf16x8*)(As + (wm + i * 16 + l15) * 32 + ko);
#pragma unroll
    for (int i = 0; i < 4; ++i)
      bfr[i] = *(const bf16x8*)(Bs + (wn + i * 16 + l15) * 32 + ko);
#pragma unroll
    for (int mi = 0; mi < 4; ++mi)
#pragma unroll
      for (int ni = 0; ni < 4; ++ni)
        acc[mi][ni] = __builtin_amdgcn_mfma_f32_16x16x32_bf16(
            af[mi], bfr[ni], acc[mi][ni], 0, 0, 0);
    __syncthreads();
  }

  // epilogue: C/D layout col=lane&15, row=quad*4+r
#pragma unroll
  for (int ni = 0; ni < 4; ++ni) {
    const int col = n0 + wn + ni * 16 + l15;
    const float bv = bias[col];
#pragma unroll
    for (int mi = 0; mi < 4; ++mi) {
      const int rowb = m0 + wm + mi * 16 + quad * 4;
#pragma unroll
      for (int r = 0; r < 4; ++r) {
        const int gr = rowb + r;
        if (gr < M) {
          const size_t idx = (size_t)gr * N + col;
          if (MODE == MODE_GB)
            C[idx] = (OutT)(acc[mi][ni][r] +
                            (gates[gr * 2] + gates[gr * 2 + 1]) * bv);
          else
            C[idx] = (OutT)(acc[mi][ni][r] + bv);
        }
      }
    }
  }
}

// ===========================================================================
// gemm_w1d: fused dual-A W1 GEMM.
//   H[M,N] = g0*gelu(X@W1^T + b1) + g1*gelu(A2@W1^T + b1)
// 128x128 tile, BK=32, 4 waves; W1 tile staged ONCE feeds both MFMA sets
// (2x arithmetic intensity vs two separate GEMMs; kills the h RMW pass).
// Requires M%128==0, N%128==0, K%32==0, grid nwg%8==0.
// ===========================================================================
__global__ __launch_bounds__(256) void gemm_w1d(
    const bf16* __restrict__ X, const bf16* __restrict__ A2,
    const bf16* __restrict__ W, const float* __restrict__ b1v,
    bf16* __restrict__ H, const float* __restrict__ gates,
    int M, int N, int K)
{
  __shared__ bf16 Xs[128 * 32];
  __shared__ bf16 Zs[128 * 32];
  __shared__ bf16 Ws[128 * 32];

  const int tid  = threadIdx.x;
  const int lane = tid & 63;
  const int w    = tid >> 6;
  const int wm   = (w & 1) * 64;
  const int wn   = (w >> 1) * 64;
  const int l15  = lane & 15;
  const int quad = lane >> 4;

  const int gx  = gridDim.x;
  const int nwg = gx * gridDim.y;
  const int cpx = nwg >> 3;
  int lin = blockIdx.y * gx + blockIdx.x;
  lin = (lin & 7) * cpx + (lin >> 3);
  const int m0 = (lin / gx) * 128;
  const int n0 = (lin % gx) * 128;

  const int sr = tid >> 2;
  const int kc = (tid & 3) * 8;
  const bf16* xp0 = X  + (size_t)(m0 + sr) * K + kc;
  const bf16* xp1 = xp0 + (size_t)64 * K;
  const bf16* zp0 = A2 + (size_t)(m0 + sr) * K + kc;
  const bf16* zp1 = zp0 + (size_t)64 * K;
  const bf16* wp0 = W  + (size_t)(n0 + sr) * K + kc;
  const bf16* wp1 = wp0 + (size_t)64 * K;
  bf16* lX0 = Xs + tid * 8;
  bf16* lX1 = Xs + 2048 + tid * 8;
  bf16* lZ0 = Zs + tid * 8;
  bf16* lZ1 = Zs + 2048 + tid * 8;
  bf16* lW0 = Ws + tid * 8;
  bf16* lW1 = Ws + 2048 + tid * 8;

  const int ko = quad * 8;

  f32x4 ax[4][4] = {};
  f32x4 az[4][4] = {};

  for (int kt = 0; kt < K; kt += 32) {
    async16(xp0 + kt, lX0);
    async16(xp1 + kt, lX1);
    async16(zp0 + kt, lZ0);
    async16(zp1 + kt, lZ1);
    async16(wp0 + kt, lW0);
    async16(wp1 + kt, lW1);
    __syncthreads();

    bf16x8 xf[4], zf[4], wf[4];
#pragma unroll
    for (int i = 0; i < 4; ++i)
      xf[i] = *(const bf16x8*)(Xs + (wm + i * 16 + l15) * 32 + ko);
#pragma unroll
    for (int i = 0; i < 4; ++i)
      zf[i] = *(const bf16x8*)(Zs + (wm + i * 16 + l15) * 32 + ko);
#pragma unroll
    for (int i = 0; i < 4; ++i)
      wf[i] = *(const bf16x8*)(Ws + (wn + i * 16 + l15) * 32 + ko);
#pragma unroll
    for (int mi = 0; mi < 4; ++mi)
#pragma unroll
      for (int ni = 0; ni < 4; ++ni) {
        ax[mi][ni] = __builtin_amdgcn_mfma_f32_16x16x32_bf16(
            xf[mi], wf[ni], ax[mi][ni], 0, 0, 0);
        az[mi][ni] = __builtin_amdgcn_mfma_f32_16x16x32_bf16(
            zf[mi], wf[ni], az[mi][ni], 0, 0, 0);
      }
    __syncthreads();
  }

#pragma unroll
  for (int ni = 0; ni < 4; ++ni) {
    const int col = n0 + wn + ni * 16 + l15;
    const float bv = b1v[col];
#pragma unroll
    for (int mi = 0; mi < 4; ++mi) {
      const int rowb = m0 + wm + mi * 16 + quad * 4;
#pragma unroll
      for (int r = 0; r < 4; ++r) {
        const int gr = rowb + r;
        float vx = ax[mi][ni][r] + bv;
        vx = 0.5f * vx * (1.0f + erff(vx * 0.70710678118654752f));
        float vz = az[mi][ni][r] + bv;
        vz = 0.5f * vz * (1.0f + erff(vz * 0.70710678118654752f));
        H[(size_t)gr * N + col] =
            (bf16)(vx * gates[gr * 2] + vz * gates[gr * 2 + 1]);
      }
    }
  }
}

// ===========================================================================
// Flash attention: grid (9 q-tiles, 16 batch, 8 heads), 64 q-rows per block.
// ===========================================================================
__global__ __launch_bounds__(256) void attn_kernel(
    const bf16* __restrict__ qp, const bf16* __restrict__ kp,
    const bf16* __restrict__ vp, bf16* __restrict__ ctx)
{
  __shared__ bf16 Qs[64 * 128];
  __shared__ bf16 Ks[64 * 128];
  __shared__ bf16 Vt[128 * 64];  // [d][key]
  __shared__ bf16 Ps[64 * 64];

  const int qt = blockIdx.x, b = blockIdx.y, h = blockIdx.z;
  const int tid = threadIdx.x, lane = tid & 63, w = tid >> 6;
  const int l15 = lane & 15, quad = lane >> 4;
  const int q0 = qt * 64;

#pragma unroll
  for (int i = 0; i < 4; ++i) {
    const int c = i * 256 + tid;
    const int row = c >> 4, col = (c & 15) * 8;
    *(bf16x8*)(Qs + row * 128 + col) =
        *(const bf16x8*)(qp + (size_t)(q0 + row) * MM + h * DH + col);
  }

  float m_r[4], l_r[4];
  f32x4 accO[8] = {};
#pragma unroll
  for (int r = 0; r < 4; ++r) { m_r[r] = -1e30f; l_r[r] = 0.f; }

  const float scale = 0.08838834764831843f;  // 1/sqrt(128)

  for (int kt = 0; kt < 9; ++kt) {
    __syncthreads();
    const int kbase = b * NQ + kt * 64;
#pragma unroll
    for (int i = 0; i < 4; ++i) {
      const int c = i * 256 + tid;
      const int row = c >> 4, col = (c & 15) * 8;
      *(bf16x8*)(Ks + row * 128 + col) =
          *(const bf16x8*)(kp + (size_t)(kbase + row) * MM + h * DH + col);
      bf16x8 vv = *(const bf16x8*)(vp + (size_t)(kbase + row) * MM + h * DH + col);
#pragma unroll
      for (int j = 0; j < 8; ++j) Vt[(col + j) * 64 + row] = vv[j];
    }
    __syncthreads();

    f32x4 sacc[4] = {};
#pragma unroll
    for (int kcq = 0; kcq < 4; ++kcq) {
      bf16x8 aq = *(const bf16x8*)(Qs + (w * 16 + l15) * 128 + kcq * 32 + quad * 8);
#pragma unroll
      for (int ni = 0; ni < 4; ++ni) {
        bf16x8 bk = *(const bf16x8*)(Ks + (ni * 16 + l15) * 128 + kcq * 32 + quad * 8);
        sacc[ni] = __builtin_amdgcn_mfma_f32_16x16x32_bf16(aq, bk, sacc[ni], 0, 0, 0);
      }
    }
#pragma unroll
    for (int ni = 0; ni < 4; ++ni)
#pragma unroll
      for (int r = 0; r < 4; ++r) sacc[ni][r] *= scale;

    float p[4][4];
#pragma unroll
    for (int r = 0; r < 4; ++r) {
      float mx = fmaxf(fmaxf(sacc[0][r], sacc[1][r]), fmaxf(sacc[2][r], sacc[3][r]));
#pragma unroll
      for (int off = 8; off >= 1; off >>= 1) mx = fmaxf(mx, __shfl_xor(mx, off, 64));
      const float mnew = fmaxf(m_r[r], mx);
      const float al = expf(m_r[r] - mnew);
      float rs = 0.f;
#pragma unroll
      for (int ni = 0; ni < 4; ++ni) { p[ni][r] = expf(sacc[ni][r] - mnew); rs += p[ni][r]; }
#pragma unroll
      for (int off = 8; off >= 1; off >>= 1) rs += __shfl_xor(rs, off, 64);
      l_r[r] = l_r[r] * al + rs;
      m_r[r] = mnew;
#pragma unroll
      for (int ni2 = 0; ni2 < 8; ++ni2) accO[ni2][r] *= al;
    }

#pragma unroll
    for (int ni = 0; ni < 4; ++ni)
#pragma unroll
      for (int r = 0; r < 4; ++r)
        Ps[(w * 16 + quad * 4 + r) * 64 + ni * 16 + l15] = (bf16)p[ni][r];

#pragma unroll
    for (int kc2 = 0; kc2 < 2; ++kc2) {
      bf16x8 ap = *(const bf16x8*)(Ps + (w * 16 + l15) * 64 + kc2 * 32 + quad * 8);
#pragma unroll
      for (int ni2 = 0; ni2 < 8; ++ni2) {
        bf16x8 bv = *(const bf16x8*)(Vt + (ni2 * 16 + l15) * 64 + kc2 * 32 + quad * 8);
        accO[ni2] = __builtin_amdgcn_mfma_f32_16x16x32_bf16(ap, bv, accO[ni2], 0, 0, 0);
      }
    }
  }

#pragma unroll
  for (int r = 0; r < 4; ++r) {
    const float inv = 1.0f / l_r[r];
    const int qrow = q0 + w * 16 + quad * 4 + r;
#pragma unroll
    for (int ni2 = 0; ni2 < 8; ++ni2)
      ctx[(size_t)(b * NQ + qrow) * MM + h * DH + ni2 * 16 + l15] =
          (bf16)(accO[ni2][r] * inv);
  }
}

// ===========================================================================
// LayerNorm kernels: f32 in, bf16 out. One block per row of 1024.
// ===========================================================================
__global__ __launch_bounds__(256) void ln_kv_kernel(
    const float* __restrict__ x, const float* __restrict__ g,
    const float* __restrict__ bta, const float* __restrict__ pos,
    bf16* __restrict__ kv, bf16* __restrict__ kin)
{
  const int row = blockIdx.x, tid = threadIdx.x;
  f32x4 xv = *(const f32x4*)(x + (size_t)row * MM + tid * 4);
  float s = 0.f, ss = 0.f;
#pragma unroll
  for (int j = 0; j < 4; ++j) { s += xv[j]; ss += xv[j] * xv[j]; }
#pragma unroll
  for (int off = 32; off >= 1; off >>= 1) { s += __shfl_xor(s, off, 64); ss += __shfl_xor(ss, off, 64); }
  __shared__ float red[8];
  const int w = tid >> 6;
  if ((tid & 63) == 0) { red[w] = s; red[4 + w] = ss; }
  __syncthreads();
  s  = red[0] + red[1] + red[2] + red[3];
  ss = red[4] + red[5] + red[6] + red[7];
  const float mu = s * (1.0f / MM);
  const float rsig = rsqrtf(ss * (1.0f / MM) - mu * mu + 1e-5f);
  const int prow = row % NQ;
#pragma unroll
  for (int j = 0; j < 4; ++j) {
    const int c = tid * 4 + j;
    const float y = (xv[j] - mu) * rsig * g[c] + bta[c];
    kv[(size_t)row * MM + c]  = (bf16)y;
    kin[(size_t)row * MM + c] = (bf16)(y + pos[(size_t)prow * MM + c]);
  }
}

__global__ __launch_bounds__(256) void ln_q_kernel(
    const float* __restrict__ query, const float* __restrict__ g,
    const float* __restrict__ bta, const float* __restrict__ pos,
    bf16* __restrict__ qout)
{
  const int row = blockIdx.x, tid = threadIdx.x;
  f32x4 xv = *(const f32x4*)(query + (size_t)row * MM + tid * 4);
  float s = 0.f, ss = 0.f;
#pragma unroll
  for (int j = 0; j < 4; ++j) { s += xv[j]; ss += xv[j] * xv[j]; }
#pragma unroll
  for (int off = 32; off >= 1; off >>= 1) { s += __shfl_xor(s, off, 64); ss += __shfl_xor(ss, off, 64); }
  __shared__ float red[8];
  const int w = tid >> 6;
  if ((tid & 63) == 0) { red[w] = s; red[4 + w] = ss; }
  __syncthreads();
  s  = red[0] + red[1] + red[2] + red[3];
  ss = red[4] + red[5] + red[6] + red[7];
  const float mu = s * (1.0f / MM);
  const float rsig = rsqrtf(ss * (1.0f / MM) - mu * mu + 1e-5f);
#pragma unroll
  for (int j = 0; j < 4; ++j) {
    const int c = tid * 4 + j;
    const float y = (xv[j] - mu) * rsig * g[c] + bta[c] + pos[(size_t)row * MM + c];
    qout[(size_t)row * MM + c] = (bf16)y;
  }
}

// ===========================================================================
// Gating (f32): softmax over 2 logits; top_k(2 of 2) == all; /(sum+1e-6)
// ===========================================================================
__global__ __launch_bounds__(256) void gating_kernel(
    const float* __restrict__ x, const float* __restrict__ wg,
    const float* __restrict__ wn, const float* __restrict__ noise,
    float* __restrict__ gates)
{
  const int row = blockIdx.x, tid = threadIdx.x;
  f32x4 xv = *(const f32x4*)(x + (size_t)row * MM + tid * 4);
  float a0 = 0, a1 = 0, c0 = 0, c1 = 0;
#pragma unroll
  for (int j = 0; j < 4; ++j) {
    const int c = tid * 4 + j;
    a0 += xv[j] * wg[c * 2];
    a1 += xv[j] * wg[c * 2 + 1];
    c0 += xv[j] * wn[c * 2];
    c1 += xv[j] * wn[c * 2 + 1];
  }
#pragma unroll
  for (int off = 32; off >= 1; off >>= 1) {
    a0 += __shfl_xor(a0, off, 64); a1 += __shfl_xor(a1, off, 64);
    c0 += __shfl_xor(c0, off, 64); c1 += __shfl_xor(c1, off, 64);
  }
  __shared__ float red[16];
  const int w = tid >> 6;
  if ((tid & 63) == 0) { red[w * 4] = a0; red[w * 4 + 1] = a1; red[w * 4 + 2] = c0; red[w * 4 + 3] = c1; }
  __syncthreads();
  if (tid == 0) {
    a0 = red[0] + red[4] + red[8] + red[12];
    a1 = red[1] + red[5] + red[9] + red[13];
    c0 = red[2] + red[6] + red[10] + red[14];
    c1 = red[3] + red[7] + red[11] + red[15];
    const float sp0 = fmaxf(c0, 0.f) + log1pf(expf(-fabsf(c0)));
    const float sp1 = fmaxf(c1, 0.f) + log1pf(expf(-fabsf(c1)));
    const float l0 = a0 + noise[row * 2]     * (sp0 + 0.01f);
    const float l1 = a1 + noise[row * 2 + 1] * (sp1 + 0.01f);
    const float mx = fmaxf(l0, l1);
    const float e0 = expf(l0 - mx), e1 = expf(l1 - mx);
    const float inv = 1.0f / (e0 + e1);
    const float p0 = e0 * inv, p1 = e1 * inv;
    const float den = 1.0f / (p0 + p1 + 1e-6f);
    gates[row * 2]     = p0 * den;
    gates[row * 2 + 1] = p1 * den;
  }
}

// ===========================================================================
extern "C" void kernel_launch(void* const* d_in, const int* in_sizes, int n_in,
                              void* d_out, int out_size, void* d_ws, size_t ws_size,
                              hipStream_t stream)
{
  const float* x       = (const float*)d_in[0];
  const float* noise   = (const float*)d_in[1];
  const float* W1      = (const float*)d_in[2];
  const float* b1      = (const float*)d_in[3];
  const float* W2      = (const float*)d_in[4];
  const float* b2      = (const float*)d_in[5];
  const float* query   = (const float*)d_in[6];
  const float* pos     = (const float*)d_in[7];
  const float* ln_q_g  = (const float*)d_in[8];
  const float* ln_q_b  = (const float*)d_in[9];
  const float* ln_kv_g = (const float*)d_in[10];
  const float* ln_kv_b = (const float*)d_in[11];
  const float* ipw     = (const float*)d_in[12];
  const float* ipb     = (const float*)d_in[13];
  const float* out_w   = (const float*)d_in[14];
  const float* out_b   = (const float*)d_in[15];
  const float* w_gate  = (const float*)d_in[16];
  const float* w_noise = (const float*)d_in[17];
  float* out = (float*)d_out;  // (16,576,4096) float32 = 150994944 B

  // Workspace layout (bytes). Attention chain runs first; the h region
  // [0, 75497472) holds kin/kp/vp/qbuf/qp/ipwb/outwb during the attention
  // phase, then h afterwards. kv and attn_out live in d_out scratch
  // (both dead before the final GB GEMM overwrites d_out).
  char* ws = (char*)d_ws;
  bf16*  kin   = (bf16*)(ws);
  bf16*  ctx   = kin;                              // after kin dead
  bf16*  kp    = (bf16*)(ws + 18874368);
  bf16*  vp    = (bf16*)(ws + 37748736);
  bf16*  qbuf  = (bf16*)(ws + 56623104);
  bf16*  qp    = (bf16*)(ws + 57802752);
  bf16*  ipwb  = (bf16*)(ws + 58982400);           // 3*1024*1024 bf16
  bf16*  outwb = (bf16*)(ws + 65273856);           // 1024*1024 bf16
  bf16*  h     = (bf16*)(ws);                      // after attention phase
  bf16*  x_bf  = (bf16*)(ws + 75497472);
  bf16*  W1b   = (bf16*)(ws + 94371840);
  bf16*  W2b   = (bf16*)(ws + 102760448);
  float* gates = (float*)(ws + 136314880);
  bf16*  kv       = (bf16*)d_out;                      // scratch, 18.9MB
  bf16*  attn_out = (bf16*)((char*)d_out + 18874368);  // scratch, 18.9MB

  // 1) gating + weight/activation converts
  gating_kernel<<<ROWS, 256, 0, stream>>>(x, w_gate, w_noise, noise, gates);
  cvt_kernel<<<9216,  256, 0, stream>>>(x,  x_bf);   // 9216*1024
  cvt_kernel<<<4096,  256, 0, stream>>>(W1, W1b);    // 4096*1024
  cvt_kernel<<<16384, 256, 0, stream>>>(W2, W2b);    // 4096*4096
  cvt_kernel<<<3072,  256, 0, stream>>>(ipw,   ipwb);
  cvt_kernel<<<1024,  256, 0, stream>>>(out_w, outwb);

  // 2) attention chain
  ln_kv_kernel<<<ROWS, 256, 0, stream>>>(x, ln_kv_g, ln_kv_b, pos, kv, kin);
  ln_q_kernel<<<NQ, 256, 0, stream>>>(query, ln_q_g, ln_q_b, pos, qbuf);

  gemm_bt<MODE_BIAS, bf16><<<dim3(8, 5),  256, 0, stream>>>(qbuf, ipwb, ipb, qp, nullptr, NQ, MM, MM);
  gemm_bt<MODE_BIAS, bf16><<<dim3(8, 72), 256, 0, stream>>>(kin, ipwb + (size_t)MM * MM, ipb + MM, kp, nullptr, ROWS, MM, MM);
  gemm_bt<MODE_BIAS, bf16><<<dim3(8, 72), 256, 0, stream>>>(kv, ipwb + (size_t)2 * MM * MM, ipb + 2 * MM, vp, nullptr, ROWS, MM, MM);

  attn_kernel<<<dim3(9, BATCH, HEADS), 256, 0, stream>>>(qp, kp, vp, ctx);

  gemm_bt<MODE_BIAS, bf16><<<dim3(8, 72), 256, 0, stream>>>(ctx, outwb, out_b, attn_out, nullptr, ROWS, MM, MM);

  // 3) combined expert branch:
  //    h   = g0*gelu(x@W1^T+b1) + g1*gelu(attn_out@W1^T+b1)   (one fused GEMM)
  //    out = h @ W2^T + (g0+g1)*b2
  gemm_w1d<<<dim3(32, 72), 256, 0, stream>>>(x_bf, attn_out, W1b, b1, h, gates, ROWS, HID, MM);
  gemm_bt<MODE_GB, float><<<dim3(32, 72), 256, 0, stream>>>(h, W2b, b2, out, gates, ROWS, HID, HID);
}

// Round 7
// 1483.080 us; speedup vs baseline: 1.0756x; 1.0756x over previous
//
#include <hip/hip_runtime.h>
#include <hip/hip_bf16.h>
#include <cstdint>
#include <cstddef>

// Round 7: round-1-verified structure (separate gating/cvt/ln_kv kernels,
// 128^2 gemm_bt with GG/GGACC/GB fused epilogues) + round-4-verified
// XCD-bijective block swizzle in gemm_bt. The lnx fusion (rounds 5/6) is
// dropped: same source failed the container twice; this round isolates it.

typedef __bf16 bf16;
typedef __bf16 bf16x4 __attribute__((ext_vector_type(4)));
typedef __bf16 bf16x8 __attribute__((ext_vector_type(8)));
typedef float  f32x4  __attribute__((ext_vector_type(4)));

#define BATCH 16
#define NQ    576
#define MM    1024
#define HID   4096
#define HEADS 8
#define DH    128
#define ROWS  (BATCH*NQ)   // 9216

// ---- async global->LDS, 16B per lane --------------------------------------
typedef const unsigned int __attribute__((address_space(1)))* gas_ptr;
typedef unsigned int __attribute__((address_space(3)))* las_ptr;

__device__ __forceinline__ void async16(const bf16* g, bf16* l) {
  __builtin_amdgcn_global_load_lds((gas_ptr)g, (las_ptr)l, 16, 0, 0);
}

// ---- f32 -> bf16 streaming convert (n % 1024 == 0) ------------------------
__global__ __launch_bounds__(256) void cvt_kernel(
    const float* __restrict__ s, bf16* __restrict__ d)
{
  const int i = (blockIdx.x * 256 + threadIdx.x) * 4;
  f32x4 v = *(const f32x4*)(s + i);
  bf16x4 o;
#pragma unroll
  for (int j = 0; j < 4; ++j) o[j] = (bf16)v[j];
  *(bf16x4*)(d + i) = o;
}

// ===========================================================================
// GEMM: C[M,N] = A[M,K] @ W[N,K]^T + bias[N], fused epilogues. A,W bf16;
// bias f32; C is OutT (bf16 intermediates, f32 final output).
// 128x128 tile, BK=32, 4 waves (2x2), 4x4 MFMA 16x16x32.
// NOTE (rounds 3+4 lesson): do NOT grow the per-wave accumulator — 4x4
// f32x4 (64 acc regs) + 72 VGPR keeps ~31% occupancy; doubling acc drops
// to 1-2 waves/SIMD and the 2-barrier structure collapses (262-657 TF).
// XCD-bijective block swizzle for L2 locality (all grids have nwg%8==0).
// Modes:
//   BIAS  : C = acc + b
//   GG    : C = g0 * gelu(acc + b)
//   GGACC : C = C + g1 * gelu(acc + b)
//   GB    : C = acc + (g0+g1) * b
// ===========================================================================
enum { MODE_BIAS = 0, MODE_GG = 1, MODE_GGACC = 2, MODE_GB = 3 };

template <int MODE, typename OutT>
__global__ __launch_bounds__(256) void gemm_bt(
    const bf16* __restrict__ A, const bf16* __restrict__ W,
    const float* __restrict__ bias, OutT* __restrict__ C,
    const float* __restrict__ gates, int M, int N, int K)
{
  __shared__ bf16 As[128 * 32];
  __shared__ bf16 Bs[128 * 32];

  const int tid  = threadIdx.x;
  const int lane = tid & 63;
  const int w    = tid >> 6;
  const int wm   = (w & 1) * 64;
  const int wn   = (w >> 1) * 64;
  const int l15  = lane & 15;
  const int quad = lane >> 4;

  // XCD-bijective swizzle: each XCD gets a contiguous chunk of the grid,
  // so neighbor blocks (sharing A/B panels) hit the same L2.
  const int gx  = gridDim.x;
  const int nwg = gx * gridDim.y;
  const int cpx = nwg >> 3;                      // nwg % 8 == 0
  int lin = blockIdx.y * gx + blockIdx.x;
  lin = (lin & 7) * cpx + (lin >> 3);
  const int m0 = (lin / gx) * 128;
  const int n0 = (lin % gx) * 128;

  f32x4 acc[4][4] = {};

  int ar0 = m0 + (tid >> 2);      if (ar0 > M - 1) ar0 = M - 1;
  int ar1 = m0 + 64 + (tid >> 2); if (ar1 > M - 1) ar1 = M - 1;
  const int kc = (tid & 3) * 8;
  const bf16* ap0 = A + (size_t)ar0 * K + kc;
  const bf16* ap1 = A + (size_t)ar1 * K + kc;
  const bf16* bp0 = W + (size_t)(n0 + (tid >> 2)) * K + kc;
  const bf16* bp1 = W + (size_t)(n0 + 64 + (tid >> 2)) * K + kc;
  bf16* lA0 = As + tid * 8;
  bf16* lA1 = As + 2048 + tid * 8;
  bf16* lB0 = Bs + tid * 8;
  bf16* lB1 = Bs + 2048 + tid * 8;

  const int ko = quad * 8;

  for (int kt = 0; kt < K; kt += 32) {
    async16(ap0 + kt, lA0);
    async16(ap1 + kt, lA1);
    async16(bp0 + kt, lB0);
    async16(bp1 + kt, lB1);
    __syncthreads();

    bf16x8 af[4], bfr[4];
#pragma unroll
    for (int i = 0; i < 4; ++i)
      af[i] = *(const bf16x8*)(As + (wm + i * 16 + l15) * 32 + ko);
#pragma unroll
    for (int i = 0; i < 4; ++i)
      bfr[i] = *(const bf16x8*)(Bs + (wn + i * 16 + l15) * 32 + ko);
#pragma unroll
    for (int mi = 0; mi < 4; ++mi)
#pragma unroll
      for (int ni = 0; ni < 4; ++ni)
        acc[mi][ni] = __builtin_amdgcn_mfma_f32_16x16x32_bf16(
            af[mi], bfr[ni], acc[mi][ni], 0, 0, 0);
    __syncthreads();
  }

  // epilogue: C/D layout col=lane&15, row=quad*4+r
#pragma unroll
  for (int ni = 0; ni < 4; ++ni) {
    const int col = n0 + wn + ni * 16 + l15;
    const float bv = bias[col];
#pragma unroll
    for (int mi = 0; mi < 4; ++mi) {
      const int rowb = m0 + wm + mi * 16 + quad * 4;
#pragma unroll
      for (int r = 0; r < 4; ++r) {
        const int gr = rowb + r;
        if (gr < M) {
          const size_t idx = (size_t)gr * N + col;
          if (MODE == MODE_GB) {
            C[idx] = (OutT)(acc[mi][ni][r] +
                            (gates[gr * 2] + gates[gr * 2 + 1]) * bv);
          } else {
            float v = acc[mi][ni][r] + bv;
            if (MODE == MODE_GG || MODE == MODE_GGACC)
              v = 0.5f * v * (1.0f + erff(v * 0.70710678118654752f));
            if (MODE == MODE_GG)
              C[idx] = (OutT)(v * gates[gr * 2]);
            else if (MODE == MODE_GGACC)
              C[idx] = (OutT)((float)C[idx] + v * gates[gr * 2 + 1]);
            else
              C[idx] = (OutT)v;
          }
        }
      }
    }
  }
}

// ===========================================================================
// Flash attention: grid (9 q-tiles, 16 batch, 8 heads), 64 q-rows per block.
// ===========================================================================
__global__ __launch_bounds__(256) void attn_kernel(
    const bf16* __restrict__ qp, const bf16* __restrict__ kp,
    const bf16* __restrict__ vp, bf16* __restrict__ ctx)
{
  __shared__ bf16 Qs[64 * 128];
  __shared__ bf16 Ks[64 * 128];
  __shared__ bf16 Vt[128 * 64];  // [d][key]
  __shared__ bf16 Ps[64 * 64];

  const int qt = blockIdx.x, b = blockIdx.y, h = blockIdx.z;
  const int tid = threadIdx.x, lane = tid & 63, w = tid >> 6;
  const int l15 = lane & 15, quad = lane >> 4;
  const int q0 = qt * 64;

#pragma unroll
  for (int i = 0; i < 4; ++i) {
    const int c = i * 256 + tid;
    const int row = c >> 4, col = (c & 15) * 8;
    *(bf16x8*)(Qs + row * 128 + col) =
        *(const bf16x8*)(qp + (size_t)(q0 + row) * MM + h * DH + col);
  }

  float m_r[4], l_r[4];
  f32x4 accO[8] = {};
#pragma unroll
  for (int r = 0; r < 4; ++r) { m_r[r] = -1e30f; l_r[r] = 0.f; }

  const float scale = 0.08838834764831843f;  // 1/sqrt(128)

  for (int kt = 0; kt < 9; ++kt) {
    __syncthreads();
    const int kbase = b * NQ + kt * 64;
#pragma unroll
    for (int i = 0; i < 4; ++i) {
      const int c = i * 256 + tid;
      const int row = c >> 4, col = (c & 15) * 8;
      *(bf16x8*)(Ks + row * 128 + col) =
          *(const bf16x8*)(kp + (size_t)(kbase + row) * MM + h * DH + col);
      bf16x8 vv = *(const bf16x8*)(vp + (size_t)(kbase + row) * MM + h * DH + col);
#pragma unroll
      for (int j = 0; j < 8; ++j) Vt[(col + j) * 64 + row] = vv[j];
    }
    __syncthreads();

    f32x4 sacc[4] = {};
#pragma unroll
    for (int kcq = 0; kcq < 4; ++kcq) {
      bf16x8 aq = *(const bf16x8*)(Qs + (w * 16 + l15) * 128 + kcq * 32 + quad * 8);
#pragma unroll
      for (int ni = 0; ni < 4; ++ni) {
        bf16x8 bk = *(const bf16x8*)(Ks + (ni * 16 + l15) * 128 + kcq * 32 + quad * 8);
        sacc[ni] = __builtin_amdgcn_mfma_f32_16x16x32_bf16(aq, bk, sacc[ni], 0, 0, 0);
      }
    }
#pragma unroll
    for (int ni = 0; ni < 4; ++ni)
#pragma unroll
      for (int r = 0; r < 4; ++r) sacc[ni][r] *= scale;

    float p[4][4];
#pragma unroll
    for (int r = 0; r < 4; ++r) {
      float mx = fmaxf(fmaxf(sacc[0][r], sacc[1][r]), fmaxf(sacc[2][r], sacc[3][r]));
#pragma unroll
      for (int off = 8; off >= 1; off >>= 1) mx = fmaxf(mx, __shfl_xor(mx, off, 64));
      const float mnew = fmaxf(m_r[r], mx);
      const float al = expf(m_r[r] - mnew);
      float rs = 0.f;
#pragma unroll
      for (int ni = 0; ni < 4; ++ni) { p[ni][r] = expf(sacc[ni][r] - mnew); rs += p[ni][r]; }
#pragma unroll
      for (int off = 8; off >= 1; off >>= 1) rs += __shfl_xor(rs, off, 64);
      l_r[r] = l_r[r] * al + rs;
      m_r[r] = mnew;
#pragma unroll
      for (int ni2 = 0; ni2 < 8; ++ni2) accO[ni2][r] *= al;
    }

#pragma unroll
    for (int ni = 0; ni < 4; ++ni)
#pragma unroll
      for (int r = 0; r < 4; ++r)
        Ps[(w * 16 + quad * 4 + r) * 64 + ni * 16 + l15] = (bf16)p[ni][r];

#pragma unroll
    for (int kc2 = 0; kc2 < 2; ++kc2) {
      bf16x8 ap = *(const bf16x8*)(Ps + (w * 16 + l15) * 64 + kc2 * 32 + quad * 8);
#pragma unroll
      for (int ni2 = 0; ni2 < 8; ++ni2) {
        bf16x8 bv = *(const bf16x8*)(Vt + (ni2 * 16 + l15) * 64 + kc2 * 32 + quad * 8);
        accO[ni2] = __builtin_amdgcn_mfma_f32_16x16x32_bf16(ap, bv, accO[ni2], 0, 0, 0);
      }
    }
  }

#pragma unroll
  for (int r = 0; r < 4; ++r) {
    const float inv = 1.0f / l_r[r];
    const int qrow = q0 + w * 16 + quad * 4 + r;
#pragma unroll
    for (int ni2 = 0; ni2 < 8; ++ni2)
      ctx[(size_t)(b * NQ + qrow) * MM + h * DH + ni2 * 16 + l15] =
          (bf16)(accO[ni2][r] * inv);
  }
}

// ===========================================================================
// LayerNorm kernels: f32 in, bf16 out. One block per row of 1024.
// ===========================================================================
__global__ __launch_bounds__(256) void ln_kv_kernel(
    const float* __restrict__ x, const float* __restrict__ g,
    const float* __restrict__ bta, const float* __restrict__ pos,
    bf16* __restrict__ kv, bf16* __restrict__ kin)
{
  const int row = blockIdx.x, tid = threadIdx.x;
  f32x4 xv = *(const f32x4*)(x + (size_t)row * MM + tid * 4);
  float s = 0.f, ss = 0.f;
#pragma unroll
  for (int j = 0; j < 4; ++j) { s += xv[j]; ss += xv[j] * xv[j]; }
#pragma unroll
  for (int off = 32; off >= 1; off >>= 1) { s += __shfl_xor(s, off, 64); ss += __shfl_xor(ss, off, 64); }
  __shared__ float red[8];
  const int w = tid >> 6;
  if ((tid & 63) == 0) { red[w] = s; red[4 + w] = ss; }
  __syncthreads();
  s  = red[0] + red[1] + red[2] + red[3];
  ss = red[4] + red[5] + red[6] + red[7];
  const float mu = s * (1.0f / MM);
  const float rsig = rsqrtf(ss * (1.0f / MM) - mu * mu + 1e-5f);
  const int prow = row % NQ;
#pragma unroll
  for (int j = 0; j < 4; ++j) {
    const int c = tid * 4 + j;
    const float y = (xv[j] - mu) * rsig * g[c] + bta[c];
    kv[(size_t)row * MM + c]  = (bf16)y;
    kin[(size_t)row * MM + c] = (bf16)(y + pos[(size_t)prow * MM + c]);
  }
}

__global__ __launch_bounds__(256) void ln_q_kernel(
    const float* __restrict__ query, const float* __restrict__ g,
    const float* __restrict__ bta, const float* __restrict__ pos,
    bf16* __restrict__ qout)
{
  const int row = blockIdx.x, tid = threadIdx.x;
  f32x4 xv = *(const f32x4*)(query + (size_t)row * MM + tid * 4);
  float s = 0.f, ss = 0.f;
#pragma unroll
  for (int j = 0; j < 4; ++j) { s += xv[j]; ss += xv[j] * xv[j]; }
#pragma unroll
  for (int off = 32; off >= 1; off >>= 1) { s += __shfl_xor(s, off, 64); ss += __shfl_xor(ss, off, 64); }
  __shared__ float red[8];
  const int w = tid >> 6;
  if ((tid & 63) == 0) { red[w] = s; red[4 + w] = ss; }
  __syncthreads();
  s  = red[0] + red[1] + red[2] + red[3];
  ss = red[4] + red[5] + red[6] + red[7];
  const float mu = s * (1.0f / MM);
  const float rsig = rsqrtf(ss * (1.0f / MM) - mu * mu + 1e-5f);
#pragma unroll
  for (int j = 0; j < 4; ++j) {
    const int c = tid * 4 + j;
    const float y = (xv[j] - mu) * rsig * g[c] + bta[c] + pos[(size_t)row * MM + c];
    qout[(size_t)row * MM + c] = (bf16)y;
  }
}

// ===========================================================================
// Gating (f32): softmax over 2 logits; top_k(2 of 2) == all; /(sum+1e-6)
// ===========================================================================
__global__ __launch_bounds__(256) void gating_kernel(
    const float* __restrict__ x, const float* __restrict__ wg,
    const float* __restrict__ wn, const float* __restrict__ noise,
    float* __restrict__ gates)
{
  const int row = blockIdx.x, tid = threadIdx.x;
  f32x4 xv = *(const f32x4*)(x + (size_t)row * MM + tid * 4);
  float a0 = 0, a1 = 0, c0 = 0, c1 = 0;
#pragma unroll
  for (int j = 0; j < 4; ++j) {
    const int c = tid * 4 + j;
    a0 += xv[j] * wg[c * 2];
    a1 += xv[j] * wg[c * 2 + 1];
    c0 += xv[j] * wn[c * 2];
    c1 += xv[j] * wn[c * 2 + 1];
  }
#pragma unroll
  for (int off = 32; off >= 1; off >>= 1) {
    a0 += __shfl_xor(a0, off, 64); a1 += __shfl_xor(a1, off, 64);
    c0 += __shfl_xor(c0, off, 64); c1 += __shfl_xor(c1, off, 64);
  }
  __shared__ float red[16];
  const int w = tid >> 6;
  if ((tid & 63) == 0) { red[w * 4] = a0; red[w * 4 + 1] = a1; red[w * 4 + 2] = c0; red[w * 4 + 3] = c1; }
  __syncthreads();
  if (tid == 0) {
    a0 = red[0] + red[4] + red[8] + red[12];
    a1 = red[1] + red[5] + red[9] + red[13];
    c0 = red[2] + red[6] + red[10] + red[14];
    c1 = red[3] + red[7] + red[11] + red[15];
    const float sp0 = fmaxf(c0, 0.f) + log1pf(expf(-fabsf(c0)));
    const float sp1 = fmaxf(c1, 0.f) + log1pf(expf(-fabsf(c1)));
    const float l0 = a0 + noise[row * 2]     * (sp0 + 0.01f);
    const float l1 = a1 + noise[row * 2 + 1] * (sp1 + 0.01f);
    const float mx = fmaxf(l0, l1);
    const float e0 = expf(l0 - mx), e1 = expf(l1 - mx);
    const float inv = 1.0f / (e0 + e1);
    const float p0 = e0 * inv, p1 = e1 * inv;
    const float den = 1.0f / (p0 + p1 + 1e-6f);
    gates[row * 2]     = p0 * den;
    gates[row * 2 + 1] = p1 * den;
  }
}

// ===========================================================================
extern "C" void kernel_launch(void* const* d_in, const int* in_sizes, int n_in,
                              void* d_out, int out_size, void* d_ws, size_t ws_size,
                              hipStream_t stream)
{
  const float* x       = (const float*)d_in[0];
  const float* noise   = (const float*)d_in[1];
  const float* W1      = (const float*)d_in[2];
  const float* b1      = (const float*)d_in[3];
  const float* W2      = (const float*)d_in[4];
  const float* b2      = (const float*)d_in[5];
  const float* query   = (const float*)d_in[6];
  const float* pos     = (const float*)d_in[7];
  const float* ln_q_g  = (const float*)d_in[8];
  const float* ln_q_b  = (const float*)d_in[9];
  const float* ln_kv_g = (const float*)d_in[10];
  const float* ln_kv_b = (const float*)d_in[11];
  const float* ipw     = (const float*)d_in[12];
  const float* ipb     = (const float*)d_in[13];
  const float* out_w   = (const float*)d_in[14];
  const float* out_b   = (const float*)d_in[15];
  const float* w_gate  = (const float*)d_in[16];
  const float* w_noise = (const float*)d_in[17];
  float* out = (float*)d_out;  // (16,576,4096) float32 = 150994944 B

  // Workspace layout (bytes). Attention chain runs first; the h region
  // [0, 75497472) holds kin/kp/vp/qbuf/qp/ipwb/outwb during the attention
  // phase, then h afterwards. kv and attn_out live in d_out scratch
  // (both dead before the final GB GEMM overwrites d_out).
  char* ws = (char*)d_ws;
  bf16*  kin   = (bf16*)(ws);
  bf16*  ctx   = kin;                              // after kin dead
  bf16*  kp    = (bf16*)(ws + 18874368);
  bf16*  vp    = (bf16*)(ws + 37748736);
  bf16*  qbuf  = (bf16*)(ws + 56623104);
  bf16*  qp    = (bf16*)(ws + 57802752);
  bf16*  ipwb  = (bf16*)(ws + 58982400);           // 3*1024*1024 bf16
  bf16*  outwb = (bf16*)(ws + 65273856);           // 1024*1024 bf16
  bf16*  h     = (bf16*)(ws);                      // after attention phase
  bf16*  x_bf  = (bf16*)(ws + 75497472);
  bf16*  W1b   = (bf16*)(ws + 94371840);
  bf16*  W2b   = (bf16*)(ws + 102760448);
  float* gates = (float*)(ws + 136314880);
  bf16*  kv       = (bf16*)d_out;                      // scratch, 18.9MB
  bf16*  attn_out = (bf16*)((char*)d_out + 18874368);  // scratch, 18.9MB

  // 1) gating + weight/activation converts
  gating_kernel<<<ROWS, 256, 0, stream>>>(x, w_gate, w_noise, noise, gates);
  cvt_kernel<<<9216,  256, 0, stream>>>(x,  x_bf);   // 9216*1024
  cvt_kernel<<<4096,  256, 0, stream>>>(W1, W1b);    // 4096*1024
  cvt_kernel<<<16384, 256, 0, stream>>>(W2, W2b);    // 4096*4096
  cvt_kernel<<<3072,  256, 0, stream>>>(ipw,   ipwb);
  cvt_kernel<<<1024,  256, 0, stream>>>(out_w, outwb);

  // 2) attention chain
  ln_kv_kernel<<<ROWS, 256, 0, stream>>>(x, ln_kv_g, ln_kv_b, pos, kv, kin);
  ln_q_kernel<<<NQ, 256, 0, stream>>>(query, ln_q_g, ln_q_b, pos, qbuf);

  gemm_bt<MODE_BIAS, bf16><<<dim3(8, 5),  256, 0, stream>>>(qbuf, ipwb, ipb, qp, nullptr, NQ, MM, MM);
  gemm_bt<MODE_BIAS, bf16><<<dim3(8, 72), 256, 0, stream>>>(kin, ipwb + (size_t)MM * MM, ipb + MM, kp, nullptr, ROWS, MM, MM);
  gemm_bt<MODE_BIAS, bf16><<<dim3(8, 72), 256, 0, stream>>>(kv, ipwb + (size_t)2 * MM * MM, ipb + 2 * MM, vp, nullptr, ROWS, MM, MM);

  attn_kernel<<<dim3(9, BATCH, HEADS), 256, 0, stream>>>(qp, kp, vp, ctx);

  gemm_bt<MODE_BIAS, bf16><<<dim3(8, 72), 256, 0, stream>>>(ctx, outwb, out_b, attn_out, nullptr, ROWS, MM, MM);

  // 3) combined expert branch:
  //    h  = g0 * gelu(x@W1^T + b1)
  //    h += g1 * gelu(attn_out@W1^T + b1)
  //    out = h @ W2^T + (g0+g1)*b2        (single big W2 GEMM)
  gemm_bt<MODE_GG,    bf16><<<dim3(32, 72), 256, 0, stream>>>(x_bf,     W1b, b1, h, gates, ROWS, HID, MM);
  gemm_bt<MODE_GGACC, bf16><<<dim3(32, 72), 256, 0, stream>>>(attn_out, W1b, b1, h, gates, ROWS, HID, MM);
  gemm_bt<MODE_GB,   float><<<dim3(32, 72), 256, 0, stream>>>(h,        W2b, b2, out, gates, ROWS, HID, HID);
}

// Round 8
// 1400.358 us; speedup vs baseline: 1.1391x; 1.0591x over previous
//
#include <hip/hip_runtime.h>
#include <hip/hip_bf16.h>
#include <cstdint>
#include <cstddef>

// Round 8: round-1 structure (NO block swizzle — round 7 measured the XCD
// swizzle at +498MB FETCH / +24us on GB: default round-robin already gives
// each XCD a perfect 4MB B-column working set since gridDim.x%8==0).
// Single delta vs round 1: lnx_kernel fuses gating + x->bf16 cvt + ln_kv.

typedef __bf16 bf16;
typedef __bf16 bf16x4 __attribute__((ext_vector_type(4)));
typedef __bf16 bf16x8 __attribute__((ext_vector_type(8)));
typedef float  f32x4  __attribute__((ext_vector_type(4)));

#define BATCH 16
#define NQ    576
#define MM    1024
#define HID   4096
#define HEADS 8
#define DH    128
#define ROWS  (BATCH*NQ)   // 9216

// ---- async global->LDS, 16B per lane --------------------------------------
typedef const unsigned int __attribute__((address_space(1)))* gas_ptr;
typedef unsigned int __attribute__((address_space(3)))* las_ptr;

__device__ __forceinline__ void async16(const bf16* g, bf16* l) {
  __builtin_amdgcn_global_load_lds((gas_ptr)g, (las_ptr)l, 16, 0, 0);
}

// ---- f32 -> bf16 streaming convert (n % 1024 == 0) ------------------------
__global__ __launch_bounds__(256) void cvt_kernel(
    const float* __restrict__ s, bf16* __restrict__ d)
{
  const int i = (blockIdx.x * 256 + threadIdx.x) * 4;
  f32x4 v = *(const f32x4*)(s + i);
  bf16x4 o;
#pragma unroll
  for (int j = 0; j < 4; ++j) o[j] = (bf16)v[j];
  *(bf16x4*)(d + i) = o;
}

// ===========================================================================
// GEMM: C[M,N] = A[M,K] @ W[N,K]^T + bias[N], fused epilogues. A,W bf16;
// bias f32; C is OutT (bf16 intermediates, f32 final output).
// 128x128 tile, BK=32, 4 waves (2x2), 4x4 MFMA 16x16x32.
// NOTE (rounds 3+4): do NOT grow the per-wave accumulator (occupancy cliff).
// NOTE (round 7): do NOT XCD-swizzle blockIdx — the natural mapping gives
// XCD = n%8, i.e. a 4MB B working set per XCD L2 (measured: swizzle
// inflated FETCH_SIZE 392->890MB).
// Modes:
//   BIAS  : C = acc + b
//   GG    : C = g0 * gelu(acc + b)
//   GGACC : C = C + g1 * gelu(acc + b)
//   GB    : C = acc + (g0+g1) * b
// ===========================================================================
enum { MODE_BIAS = 0, MODE_GG = 1, MODE_GGACC = 2, MODE_GB = 3 };

template <int MODE, typename OutT>
__global__ __launch_bounds__(256) void gemm_bt(
    const bf16* __restrict__ A, const bf16* __restrict__ W,
    const float* __restrict__ bias, OutT* __restrict__ C,
    const float* __restrict__ gates, int M, int N, int K)
{
  __shared__ bf16 As[128 * 32];
  __shared__ bf16 Bs[128 * 32];

  const int tid  = threadIdx.x;
  const int lane = tid & 63;
  const int w    = tid >> 6;
  const int wm   = (w & 1) * 64;
  const int wn   = (w >> 1) * 64;
  const int l15  = lane & 15;
  const int quad = lane >> 4;
  const int m0   = blockIdx.y * 128;
  const int n0   = blockIdx.x * 128;

  f32x4 acc[4][4] = {};

  int ar0 = m0 + (tid >> 2);      if (ar0 > M - 1) ar0 = M - 1;
  int ar1 = m0 + 64 + (tid >> 2); if (ar1 > M - 1) ar1 = M - 1;
  const int kc = (tid & 3) * 8;
  const bf16* ap0 = A + (size_t)ar0 * K + kc;
  const bf16* ap1 = A + (size_t)ar1 * K + kc;
  const bf16* bp0 = W + (size_t)(n0 + (tid >> 2)) * K + kc;
  const bf16* bp1 = W + (size_t)(n0 + 64 + (tid >> 2)) * K + kc;
  bf16* lA0 = As + tid * 8;
  bf16* lA1 = As + 2048 + tid * 8;
  bf16* lB0 = Bs + tid * 8;
  bf16* lB1 = Bs + 2048 + tid * 8;

  const int ko = quad * 8;

  for (int kt = 0; kt < K; kt += 32) {
    async16(ap0 + kt, lA0);
    async16(ap1 + kt, lA1);
    async16(bp0 + kt, lB0);
    async16(bp1 + kt, lB1);
    __syncthreads();

    bf16x8 af[4], bfr[4];
#pragma unroll
    for (int i = 0; i < 4; ++i)
      af[i] = *(const bf16x8*)(As + (wm + i * 16 + l15) * 32 + ko);
#pragma unroll
    for (int i = 0; i < 4; ++i)
      bfr[i] = *(const bf16x8*)(Bs + (wn + i * 16 + l15) * 32 + ko);
#pragma unroll
    for (int mi = 0; mi < 4; ++mi)
#pragma unroll
      for (int ni = 0; ni < 4; ++ni)
        acc[mi][ni] = __builtin_amdgcn_mfma_f32_16x16x32_bf16(
            af[mi], bfr[ni], acc[mi][ni], 0, 0, 0);
    __syncthreads();
  }

  // epilogue: C/D layout col=lane&15, row=quad*4+r
#pragma unroll
  for (int ni = 0; ni < 4; ++ni) {
    const int col = n0 + wn + ni * 16 + l15;
    const float bv = bias[col];
#pragma unroll
    for (int mi = 0; mi < 4; ++mi) {
      const int rowb = m0 + wm + mi * 16 + quad * 4;
#pragma unroll
      for (int r = 0; r < 4; ++r) {
        const int gr = rowb + r;
        if (gr < M) {
          const size_t idx = (size_t)gr * N + col;
          if (MODE == MODE_GB) {
            C[idx] = (OutT)(acc[mi][ni][r] +
                            (gates[gr * 2] + gates[gr * 2 + 1]) * bv);
          } else {
            float v = acc[mi][ni][r] + bv;
            if (MODE == MODE_GG || MODE == MODE_GGACC)
              v = 0.5f * v * (1.0f + erff(v * 0.70710678118654752f));
            if (MODE == MODE_GG)
              C[idx] = (OutT)(v * gates[gr * 2]);
            else if (MODE == MODE_GGACC)
              C[idx] = (OutT)((float)C[idx] + v * gates[gr * 2 + 1]);
            else
              C[idx] = (OutT)v;
          }
        }
      }
    }
  }
}

// ===========================================================================
// Flash attention: grid (9 q-tiles, 16 batch, 8 heads), 64 q-rows per block.
// ===========================================================================
__global__ __launch_bounds__(256) void attn_kernel(
    const bf16* __restrict__ qp, const bf16* __restrict__ kp,
    const bf16* __restrict__ vp, bf16* __restrict__ ctx)
{
  __shared__ bf16 Qs[64 * 128];
  __shared__ bf16 Ks[64 * 128];
  __shared__ bf16 Vt[128 * 64];  // [d][key]
  __shared__ bf16 Ps[64 * 64];

  const int qt = blockIdx.x, b = blockIdx.y, h = blockIdx.z;
  const int tid = threadIdx.x, lane = tid & 63, w = tid >> 6;
  const int l15 = lane & 15, quad = lane >> 4;
  const int q0 = qt * 64;

#pragma unroll
  for (int i = 0; i < 4; ++i) {
    const int c = i * 256 + tid;
    const int row = c >> 4, col = (c & 15) * 8;
    *(bf16x8*)(Qs + row * 128 + col) =
        *(const bf16x8*)(qp + (size_t)(q0 + row) * MM + h * DH + col);
  }

  float m_r[4], l_r[4];
  f32x4 accO[8] = {};
#pragma unroll
  for (int r = 0; r < 4; ++r) { m_r[r] = -1e30f; l_r[r] = 0.f; }

  const float scale = 0.08838834764831843f;  // 1/sqrt(128)

  for (int kt = 0; kt < 9; ++kt) {
    __syncthreads();
    const int kbase = b * NQ + kt * 64;
#pragma unroll
    for (int i = 0; i < 4; ++i) {
      const int c = i * 256 + tid;
      const int row = c >> 4, col = (c & 15) * 8;
      *(bf16x8*)(Ks + row * 128 + col) =
          *(const bf16x8*)(kp + (size_t)(kbase + row) * MM + h * DH + col);
      bf16x8 vv = *(const bf16x8*)(vp + (size_t)(kbase + row) * MM + h * DH + col);
#pragma unroll
      for (int j = 0; j < 8; ++j) Vt[(col + j) * 64 + row] = vv[j];
    }
    __syncthreads();

    f32x4 sacc[4] = {};
#pragma unroll
    for (int kcq = 0; kcq < 4; ++kcq) {
      bf16x8 aq = *(const bf16x8*)(Qs + (w * 16 + l15) * 128 + kcq * 32 + quad * 8);
#pragma unroll
      for (int ni = 0; ni < 4; ++ni) {
        bf16x8 bk = *(const bf16x8*)(Ks + (ni * 16 + l15) * 128 + kcq * 32 + quad * 8);
        sacc[ni] = __builtin_amdgcn_mfma_f32_16x16x32_bf16(aq, bk, sacc[ni], 0, 0, 0);
      }
    }
#pragma unroll
    for (int ni = 0; ni < 4; ++ni)
#pragma unroll
      for (int r = 0; r < 4; ++r) sacc[ni][r] *= scale;

    float p[4][4];
#pragma unroll
    for (int r = 0; r < 4; ++r) {
      float mx = fmaxf(fmaxf(sacc[0][r], sacc[1][r]), fmaxf(sacc[2][r], sacc[3][r]));
#pragma unroll
      for (int off = 8; off >= 1; off >>= 1) mx = fmaxf(mx, __shfl_xor(mx, off, 64));
      const float mnew = fmaxf(m_r[r], mx);
      const float al = expf(m_r[r] - mnew);
      float rs = 0.f;
#pragma unroll
      for (int ni = 0; ni < 4; ++ni) { p[ni][r] = expf(sacc[ni][r] - mnew); rs += p[ni][r]; }
#pragma unroll
      for (int off = 8; off >= 1; off >>= 1) rs += __shfl_xor(rs, off, 64);
      l_r[r] = l_r[r] * al + rs;
      m_r[r] = mnew;
#pragma unroll
      for (int ni2 = 0; ni2 < 8; ++ni2) accO[ni2][r] *= al;
    }

#pragma unroll
    for (int ni = 0; ni < 4; ++ni)
#pragma unroll
      for (int r = 0; r < 4; ++r)
        Ps[(w * 16 + quad * 4 + r) * 64 + ni * 16 + l15] = (bf16)p[ni][r];

#pragma unroll
    for (int kc2 = 0; kc2 < 2; ++kc2) {
      bf16x8 ap = *(const bf16x8*)(Ps + (w * 16 + l15) * 64 + kc2 * 32 + quad * 8);
#pragma unroll
      for (int ni2 = 0; ni2 < 8; ++ni2) {
        bf16x8 bv = *(const bf16x8*)(Vt + (ni2 * 16 + l15) * 64 + kc2 * 32 + quad * 8);
        accO[ni2] = __builtin_amdgcn_mfma_f32_16x16x32_bf16(ap, bv, accO[ni2], 0, 0, 0);
      }
    }
  }

#pragma unroll
  for (int r = 0; r < 4; ++r) {
    const float inv = 1.0f / l_r[r];
    const int qrow = q0 + w * 16 + quad * 4 + r;
#pragma unroll
    for (int ni2 = 0; ni2 < 8; ++ni2)
      ctx[(size_t)(b * NQ + qrow) * MM + h * DH + ni2 * 16 + l15] =
          (bf16)(accO[ni2][r] * inv);
  }
}

// ===========================================================================
// Fused x-row pass: LayerNorm(kv) + kin(+pos) + x_bf convert + gating.
// One block per row of 1024; reads x exactly once.
// ===========================================================================
__global__ __launch_bounds__(256) void lnx_kernel(
    const float* __restrict__ x, const float* __restrict__ g,
    const float* __restrict__ bta, const float* __restrict__ pos,
    const float* __restrict__ wg, const float* __restrict__ wn,
    const float* __restrict__ noise,
    bf16* __restrict__ kv, bf16* __restrict__ kin,
    bf16* __restrict__ x_bf, float* __restrict__ gates)
{
  const int row = blockIdx.x, tid = threadIdx.x;
  f32x4 xv = *(const f32x4*)(x + (size_t)row * MM + tid * 4);

  float s = 0.f, ss = 0.f, a0 = 0.f, a1 = 0.f, c0 = 0.f, c1 = 0.f;
#pragma unroll
  for (int j = 0; j < 4; ++j) {
    const int c = tid * 4 + j;
    s  += xv[j];
    ss += xv[j] * xv[j];
    a0 += xv[j] * wg[c * 2];
    a1 += xv[j] * wg[c * 2 + 1];
    c0 += xv[j] * wn[c * 2];
    c1 += xv[j] * wn[c * 2 + 1];
  }

  // x_bf convert (free: xv already in registers)
  {
    bf16x4 o;
#pragma unroll
    for (int j = 0; j < 4; ++j) o[j] = (bf16)xv[j];
    *(bf16x4*)(x_bf + (size_t)row * MM + tid * 4) = o;
  }

#pragma unroll
  for (int off = 32; off >= 1; off >>= 1) {
    s  += __shfl_xor(s,  off, 64);  ss += __shfl_xor(ss, off, 64);
    a0 += __shfl_xor(a0, off, 64);  a1 += __shfl_xor(a1, off, 64);
    c0 += __shfl_xor(c0, off, 64);  c1 += __shfl_xor(c1, off, 64);
  }
  __shared__ float red[24];
  const int w = tid >> 6;
  if ((tid & 63) == 0) {
    red[w * 6]     = s;  red[w * 6 + 1] = ss;
    red[w * 6 + 2] = a0; red[w * 6 + 3] = a1;
    red[w * 6 + 4] = c0; red[w * 6 + 5] = c1;
  }
  __syncthreads();
  s  = red[0] + red[6]  + red[12] + red[18];
  ss = red[1] + red[7]  + red[13] + red[19];

  const float mu   = s * (1.0f / MM);
  const float rsig = rsqrtf(ss * (1.0f / MM) - mu * mu + 1e-5f);
  const int prow = row % NQ;
#pragma unroll
  for (int j = 0; j < 4; ++j) {
    const int c = tid * 4 + j;
    const float y = (xv[j] - mu) * rsig * g[c] + bta[c];
    kv[(size_t)row * MM + c]  = (bf16)y;
    kin[(size_t)row * MM + c] = (bf16)(y + pos[(size_t)prow * MM + c]);
  }

  if (tid == 0) {
    a0 = red[2] + red[8]  + red[14] + red[20];
    a1 = red[3] + red[9]  + red[15] + red[21];
    c0 = red[4] + red[10] + red[16] + red[22];
    c1 = red[5] + red[11] + red[17] + red[23];
    const float sp0 = fmaxf(c0, 0.f) + log1pf(expf(-fabsf(c0)));
    const float sp1 = fmaxf(c1, 0.f) + log1pf(expf(-fabsf(c1)));
    const float l0 = a0 + noise[row * 2]     * (sp0 + 0.01f);
    const float l1 = a1 + noise[row * 2 + 1] * (sp1 + 0.01f);
    const float mx = fmaxf(l0, l1);
    const float e0 = expf(l0 - mx), e1 = expf(l1 - mx);
    const float inv = 1.0f / (e0 + e1);
    const float p0 = e0 * inv, p1 = e1 * inv;
    const float den = 1.0f / (p0 + p1 + 1e-6f);
    gates[row * 2]     = p0 * den;
    gates[row * 2 + 1] = p1 * den;
  }
}

__global__ __launch_bounds__(256) void ln_q_kernel(
    const float* __restrict__ query, const float* __restrict__ g,
    const float* __restrict__ bta, const float* __restrict__ pos,
    bf16* __restrict__ qout)
{
  const int row = blockIdx.x, tid = threadIdx.x;
  f32x4 xv = *(const f32x4*)(query + (size_t)row * MM + tid * 4);
  float s = 0.f, ss = 0.f;
#pragma unroll
  for (int j = 0; j < 4; ++j) { s += xv[j]; ss += xv[j] * xv[j]; }
#pragma unroll
  for (int off = 32; off >= 1; off >>= 1) { s += __shfl_xor(s, off, 64); ss += __shfl_xor(ss, off, 64); }
  __shared__ float red[8];
  const int w = tid >> 6;
  if ((tid & 63) == 0) { red[w] = s; red[4 + w] = ss; }
  __syncthreads();
  s  = red[0] + red[1] + red[2] + red[3];
  ss = red[4] + red[5] + red[6] + red[7];
  const float mu = s * (1.0f / MM);
  const float rsig = rsqrtf(ss * (1.0f / MM) - mu * mu + 1e-5f);
#pragma unroll
  for (int j = 0; j < 4; ++j) {
    const int c = tid * 4 + j;
    const float y = (xv[j] - mu) * rsig * g[c] + bta[c] + pos[(size_t)row * MM + c];
    qout[(size_t)row * MM + c] = (bf16)y;
  }
}

// ===========================================================================
extern "C" void kernel_launch(void* const* d_in, const int* in_sizes, int n_in,
                              void* d_out, int out_size, void* d_ws, size_t ws_size,
                              hipStream_t stream)
{
  const float* x       = (const float*)d_in[0];
  const float* noise   = (const float*)d_in[1];
  const float* W1      = (const float*)d_in[2];
  const float* b1      = (const float*)d_in[3];
  const float* W2      = (const float*)d_in[4];
  const float* b2      = (const float*)d_in[5];
  const float* query   = (const float*)d_in[6];
  const float* pos     = (const float*)d_in[7];
  const float* ln_q_g  = (const float*)d_in[8];
  const float* ln_q_b  = (const float*)d_in[9];
  const float* ln_kv_g = (const float*)d_in[10];
  const float* ln_kv_b = (const float*)d_in[11];
  const float* ipw     = (const float*)d_in[12];
  const float* ipb     = (const float*)d_in[13];
  const float* out_w   = (const float*)d_in[14];
  const float* out_b   = (const float*)d_in[15];
  const float* w_gate  = (const float*)d_in[16];
  const float* w_noise = (const float*)d_in[17];
  float* out = (float*)d_out;  // (16,576,4096) float32 = 150994944 B

  // Workspace layout (bytes). Attention chain runs first; the h region
  // [0, 75497472) holds kin/kp/vp/qbuf/qp/ipwb/outwb during the attention
  // phase, then h afterwards. kv and attn_out live in d_out scratch
  // (both dead before the final GB GEMM overwrites d_out).
  char* ws = (char*)d_ws;
  bf16*  kin   = (bf16*)(ws);
  bf16*  ctx   = kin;                              // after kin dead
  bf16*  kp    = (bf16*)(ws + 18874368);
  bf16*  vp    = (bf16*)(ws + 37748736);
  bf16*  qbuf  = (bf16*)(ws + 56623104);
  bf16*  qp    = (bf16*)(ws + 57802752);
  bf16*  ipwb  = (bf16*)(ws + 58982400);           // 3*1024*1024 bf16
  bf16*  outwb = (bf16*)(ws + 65273856);           // 1024*1024 bf16
  bf16*  h     = (bf16*)(ws);                      // after attention phase
  bf16*  x_bf  = (bf16*)(ws + 75497472);
  bf16*  W1b   = (bf16*)(ws + 94371840);
  bf16*  W2b   = (bf16*)(ws + 102760448);
  float* gates = (float*)(ws + 136314880);
  bf16*  kv       = (bf16*)d_out;                      // scratch, 18.9MB
  bf16*  attn_out = (bf16*)((char*)d_out + 18874368);  // scratch, 18.9MB

  // 1) weight converts + fused x pass (LN + x_bf + gating)
  cvt_kernel<<<4096,  256, 0, stream>>>(W1, W1b);    // 4096*1024
  cvt_kernel<<<16384, 256, 0, stream>>>(W2, W2b);    // 4096*4096
  cvt_kernel<<<3072,  256, 0, stream>>>(ipw,   ipwb);
  cvt_kernel<<<1024,  256, 0, stream>>>(out_w, outwb);
  lnx_kernel<<<ROWS, 256, 0, stream>>>(x, ln_kv_g, ln_kv_b, pos,
                                       w_gate, w_noise, noise,
                                       kv, kin, x_bf, gates);
  ln_q_kernel<<<NQ, 256, 0, stream>>>(query, ln_q_g, ln_q_b, pos, qbuf);

  // 2) attention chain
  gemm_bt<MODE_BIAS, bf16><<<dim3(8, 5),  256, 0, stream>>>(qbuf, ipwb, ipb, qp, nullptr, NQ, MM, MM);
  gemm_bt<MODE_BIAS, bf16><<<dim3(8, 72), 256, 0, stream>>>(kin, ipwb + (size_t)MM * MM, ipb + MM, kp, nullptr, ROWS, MM, MM);
  gemm_bt<MODE_BIAS, bf16><<<dim3(8, 72), 256, 0, stream>>>(kv, ipwb + (size_t)2 * MM * MM, ipb + 2 * MM, vp, nullptr, ROWS, MM, MM);

  attn_kernel<<<dim3(9, BATCH, HEADS), 256, 0, stream>>>(qp, kp, vp, ctx);

  gemm_bt<MODE_BIAS, bf16><<<dim3(8, 72), 256, 0, stream>>>(ctx, outwb, out_b, attn_out, nullptr, ROWS, MM, MM);

  // 3) combined expert branch:
  //    h  = g0 * gelu(x@W1^T + b1)
  //    h += g1 * gelu(attn_out@W1^T + b1)
  //    out = h @ W2^T + (g0+g1)*b2        (single big W2 GEMM)
  gemm_bt<MODE_GG,    bf16><<<dim3(32, 72), 256, 0, stream>>>(x_bf,     W1b, b1, h, gates, ROWS, HID, MM);
  gemm_bt<MODE_GGACC, bf16><<<dim3(32, 72), 256, 0, stream>>>(attn_out, W1b, b1, h, gates, ROWS, HID, MM);
  gemm_bt<MODE_GB,   float><<<dim3(32, 72), 256, 0, stream>>>(h,        W2b, b2, out, gates, ROWS, HID, HID);
}

// Round 9
// 1335.076 us; speedup vs baseline: 1.1948x; 1.0489x over previous
//
#include <hip/hip_runtime.h>
#include <hip/hip_bf16.h>
#include <cstdint>
#include <cstddef>

// Round 9: single delta vs round-8 (1400us verified): gemm_bt BK 32->64.
// Halves the per-K-step vmcnt(0)+barrier drains (the m97-structure stall).
// 128B LDS rows require the 3-bit XOR chunk swizzle (pre-swizzled global
// source + same XOR on ds_read; linear gload_lds dest) to avoid a 16-way
// bank conflict. LDS 32KB/block keeps occupancy VGPR-limited (unchanged).

typedef __bf16 bf16;
typedef __bf16 bf16x4 __attribute__((ext_vector_type(4)));
typedef __bf16 bf16x8 __attribute__((ext_vector_type(8)));
typedef float  f32x4  __attribute__((ext_vector_type(4)));

#define BATCH 16
#define NQ    576
#define MM    1024
#define HID   4096
#define HEADS 8
#define DH    128
#define ROWS  (BATCH*NQ)   // 9216

// ---- async global->LDS, 16B per lane --------------------------------------
typedef const unsigned int __attribute__((address_space(1)))* gas_ptr;
typedef unsigned int __attribute__((address_space(3)))* las_ptr;

__device__ __forceinline__ void async16(const bf16* g, bf16* l) {
  __builtin_amdgcn_global_load_lds((gas_ptr)g, (las_ptr)l, 16, 0, 0);
}

// ---- f32 -> bf16 streaming convert (n % 1024 == 0) ------------------------
__global__ __launch_bounds__(256) void cvt_kernel(
    const float* __restrict__ s, bf16* __restrict__ d)
{
  const int i = (blockIdx.x * 256 + threadIdx.x) * 4;
  f32x4 v = *(const f32x4*)(s + i);
  bf16x4 o;
#pragma unroll
  for (int j = 0; j < 4; ++j) o[j] = (bf16)v[j];
  *(bf16x4*)(d + i) = o;
}

// ===========================================================================
// GEMM: C[M,N] = A[M,K] @ W[N,K]^T + bias[N], fused epilogues.
// 128x128 tile, BK=64, 4 waves (2x2), 4x4 MFMA 16x16x32, 2 k-halves/iter.
// LDS layout: row r (64 bf16 = 8 chunks of 16B); slot s holds global chunk
// s ^ (r&7) — involution applied on the staging SOURCE and on ds_read.
// NOTE (r3+r4): do NOT grow the accumulator (occupancy cliff 31%->12%).
// NOTE (r7): do NOT XCD-swizzle blockIdx (natural map: XCD=n%8 -> 4MB
// B-set/XCD L2; swizzle doubled FETCH_SIZE).
// Modes: BIAS / GG (g0*gelu) / GGACC (+= g1*gelu) / GB (acc+(g0+g1)*b).
// ===========================================================================
enum { MODE_BIAS = 0, MODE_GG = 1, MODE_GGACC = 2, MODE_GB = 3 };

template <int MODE, typename OutT>
__global__ __launch_bounds__(256) void gemm_bt(
    const bf16* __restrict__ A, const bf16* __restrict__ W,
    const float* __restrict__ bias, OutT* __restrict__ C,
    const float* __restrict__ gates, int M, int N, int K)
{
  __shared__ bf16 As[128 * 64];
  __shared__ bf16 Bs[128 * 64];

  const int tid  = threadIdx.x;
  const int lane = tid & 63;
  const int w    = tid >> 6;
  const int wm   = (w & 1) * 64;
  const int wn   = (w >> 1) * 64;
  const int l15  = lane & 15;
  const int quad = lane >> 4;
  const int m0   = blockIdx.y * 128;
  const int n0   = blockIdx.x * 128;

  f32x4 acc[4][4] = {};

  // ---- staging: chunk c = j*256+tid (j=0..3), row = j*32 + tid/8,
  // slot = tid&7; source chunk = slot ^ (row&7)  (row&7 == (tid>>3)&7).
  const int srow0  = tid >> 3;                       // 0..31
  const int schunk = (tid & 7) ^ (srow0 & 7);
  int arows[4], brows[4];
#pragma unroll
  for (int j = 0; j < 4; ++j) {
    int r = m0 + j * 32 + srow0; if (r > M - 1) r = M - 1;
    arows[j] = r;
    brows[j] = n0 + j * 32 + srow0;                  // N tiles always full
  }
  const int kc = schunk * 8;
  bf16* lA = As + tid * 8;                           // + j*2048 elements
  bf16* lB = Bs + tid * 8;

  // ---- fragment read offsets: row*64 + ((h*4+quad)^(l15&7))*8 elements
  const int axb  = (quad ^ (l15 & 7)) * 8;           // k-half 0
  const int axb1 = axb ^ 32;                         // k-half 1

  for (int kt = 0; kt < K; kt += 64) {
#pragma unroll
    for (int j = 0; j < 4; ++j)
      async16(A + (size_t)arows[j] * K + kt + kc, lA + j * 2048);
#pragma unroll
    for (int j = 0; j < 4; ++j)
      async16(W + (size_t)brows[j] * K + kt + kc, lB + j * 2048);
    __syncthreads();

    bf16x8 af[4], bfr[4];
    // k-half 0
#pragma unroll
    for (int i = 0; i < 4; ++i)
      af[i] = *(const bf16x8*)(As + (wm + i * 16 + l15) * 64 + axb);
#pragma unroll
    for (int i = 0; i < 4; ++i)
      bfr[i] = *(const bf16x8*)(Bs + (wn + i * 16 + l15) * 64 + axb);
#pragma unroll
    for (int mi = 0; mi < 4; ++mi)
#pragma unroll
      for (int ni = 0; ni < 4; ++ni)
        acc[mi][ni] = __builtin_amdgcn_mfma_f32_16x16x32_bf16(
            af[mi], bfr[ni], acc[mi][ni], 0, 0, 0);
    // k-half 1
#pragma unroll
    for (int i = 0; i < 4; ++i)
      af[i] = *(const bf16x8*)(As + (wm + i * 16 + l15) * 64 + axb1);
#pragma unroll
    for (int i = 0; i < 4; ++i)
      bfr[i] = *(const bf16x8*)(Bs + (wn + i * 16 + l15) * 64 + axb1);
#pragma unroll
    for (int mi = 0; mi < 4; ++mi)
#pragma unroll
      for (int ni = 0; ni < 4; ++ni)
        acc[mi][ni] = __builtin_amdgcn_mfma_f32_16x16x32_bf16(
            af[mi], bfr[ni], acc[mi][ni], 0, 0, 0);
    __syncthreads();
  }

  // epilogue: C/D layout col=lane&15, row=quad*4+r
#pragma unroll
  for (int ni = 0; ni < 4; ++ni) {
    const int col = n0 + wn + ni * 16 + l15;
    const float bv = bias[col];
#pragma unroll
    for (int mi = 0; mi < 4; ++mi) {
      const int rowb = m0 + wm + mi * 16 + quad * 4;
#pragma unroll
      for (int r = 0; r < 4; ++r) {
        const int gr = rowb + r;
        if (gr < M) {
          const size_t idx = (size_t)gr * N + col;
          if (MODE == MODE_GB) {
            C[idx] = (OutT)(acc[mi][ni][r] +
                            (gates[gr * 2] + gates[gr * 2 + 1]) * bv);
          } else {
            float v = acc[mi][ni][r] + bv;
            if (MODE == MODE_GG || MODE == MODE_GGACC)
              v = 0.5f * v * (1.0f + erff(v * 0.70710678118654752f));
            if (MODE == MODE_GG)
              C[idx] = (OutT)(v * gates[gr * 2]);
            else if (MODE == MODE_GGACC)
              C[idx] = (OutT)((float)C[idx] + v * gates[gr * 2 + 1]);
            else
              C[idx] = (OutT)v;
          }
        }
      }
    }
  }
}

// ===========================================================================
// Flash attention: grid (9 q-tiles, 16 batch, 8 heads), 64 q-rows per block.
// ===========================================================================
__global__ __launch_bounds__(256) void attn_kernel(
    const bf16* __restrict__ qp, const bf16* __restrict__ kp,
    const bf16* __restrict__ vp, bf16* __restrict__ ctx)
{
  __shared__ bf16 Qs[64 * 128];
  __shared__ bf16 Ks[64 * 128];
  __shared__ bf16 Vt[128 * 64];  // [d][key]
  __shared__ bf16 Ps[64 * 64];

  const int qt = blockIdx.x, b = blockIdx.y, h = blockIdx.z;
  const int tid = threadIdx.x, lane = tid & 63, w = tid >> 6;
  const int l15 = lane & 15, quad = lane >> 4;
  const int q0 = qt * 64;

#pragma unroll
  for (int i = 0; i < 4; ++i) {
    const int c = i * 256 + tid;
    const int row = c >> 4, col = (c & 15) * 8;
    *(bf16x8*)(Qs + row * 128 + col) =
        *(const bf16x8*)(qp + (size_t)(q0 + row) * MM + h * DH + col);
  }

  float m_r[4], l_r[4];
  f32x4 accO[8] = {};
#pragma unroll
  for (int r = 0; r < 4; ++r) { m_r[r] = -1e30f; l_r[r] = 0.f; }

  const float scale = 0.08838834764831843f;  // 1/sqrt(128)

  for (int kt = 0; kt < 9; ++kt) {
    __syncthreads();
    const int kbase = b * NQ + kt * 64;
#pragma unroll
    for (int i = 0; i < 4; ++i) {
      const int c = i * 256 + tid;
      const int row = c >> 4, col = (c & 15) * 8;
      *(bf16x8*)(Ks + row * 128 + col) =
          *(const bf16x8*)(kp + (size_t)(kbase + row) * MM + h * DH + col);
      bf16x8 vv = *(const bf16x8*)(vp + (size_t)(kbase + row) * MM + h * DH + col);
#pragma unroll
      for (int j = 0; j < 8; ++j) Vt[(col + j) * 64 + row] = vv[j];
    }
    __syncthreads();

    f32x4 sacc[4] = {};
#pragma unroll
    for (int kcq = 0; kcq < 4; ++kcq) {
      bf16x8 aq = *(const bf16x8*)(Qs + (w * 16 + l15) * 128 + kcq * 32 + quad * 8);
#pragma unroll
      for (int ni = 0; ni < 4; ++ni) {
        bf16x8 bk = *(const bf16x8*)(Ks + (ni * 16 + l15) * 128 + kcq * 32 + quad * 8);
        sacc[ni] = __builtin_amdgcn_mfma_f32_16x16x32_bf16(aq, bk, sacc[ni], 0, 0, 0);
      }
    }
#pragma unroll
    for (int ni = 0; ni < 4; ++ni)
#pragma unroll
      for (int r = 0; r < 4; ++r) sacc[ni][r] *= scale;

    float p[4][4];
#pragma unroll
    for (int r = 0; r < 4; ++r) {
      float mx = fmaxf(fmaxf(sacc[0][r], sacc[1][r]), fmaxf(sacc[2][r], sacc[3][r]));
#pragma unroll
      for (int off = 8; off >= 1; off >>= 1) mx = fmaxf(mx, __shfl_xor(mx, off, 64));
      const float mnew = fmaxf(m_r[r], mx);
      const float al = expf(m_r[r] - mnew);
      float rs = 0.f;
#pragma unroll
      for (int ni = 0; ni < 4; ++ni) { p[ni][r] = expf(sacc[ni][r] - mnew); rs += p[ni][r]; }
#pragma unroll
      for (int off = 8; off >= 1; off >>= 1) rs += __shfl_xor(rs, off, 64);
      l_r[r] = l_r[r] * al + rs;
      m_r[r] = mnew;
#pragma unroll
      for (int ni2 = 0; ni2 < 8; ++ni2) accO[ni2][r] *= al;
    }

#pragma unroll
    for (int ni = 0; ni < 4; ++ni)
#pragma unroll
      for (int r = 0; r < 4; ++r)
        Ps[(w * 16 + quad * 4 + r) * 64 + ni * 16 + l15] = (bf16)p[ni][r];

#pragma unroll
    for (int kc2 = 0; kc2 < 2; ++kc2) {
      bf16x8 ap = *(const bf16x8*)(Ps + (w * 16 + l15) * 64 + kc2 * 32 + quad * 8);
#pragma unroll
      for (int ni2 = 0; ni2 < 8; ++ni2) {
        bf16x8 bv = *(const bf16x8*)(Vt + (ni2 * 16 + l15) * 64 + kc2 * 32 + quad * 8);
        accO[ni2] = __builtin_amdgcn_mfma_f32_16x16x32_bf16(ap, bv, accO[ni2], 0, 0, 0);
      }
    }
  }

#pragma unroll
  for (int r = 0; r < 4; ++r) {
    const float inv = 1.0f / l_r[r];
    const int qrow = q0 + w * 16 + quad * 4 + r;
#pragma unroll
    for (int ni2 = 0; ni2 < 8; ++ni2)
      ctx[(size_t)(b * NQ + qrow) * MM + h * DH + ni2 * 16 + l15] =
          (bf16)(accO[ni2][r] * inv);
  }
}

// ===========================================================================
// Fused x-row pass: LayerNorm(kv) + kin(+pos) + x_bf convert + gating.
// One block per row of 1024; reads x exactly once.
// ===========================================================================
__global__ __launch_bounds__(256) void lnx_kernel(
    const float* __restrict__ x, const float* __restrict__ g,
    const float* __restrict__ bta, const float* __restrict__ pos,
    const float* __restrict__ wg, const float* __restrict__ wn,
    const float* __restrict__ noise,
    bf16* __restrict__ kv, bf16* __restrict__ kin,
    bf16* __restrict__ x_bf, float* __restrict__ gates)
{
  const int row = blockIdx.x, tid = threadIdx.x;
  f32x4 xv = *(const f32x4*)(x + (size_t)row * MM + tid * 4);

  float s = 0.f, ss = 0.f, a0 = 0.f, a1 = 0.f, c0 = 0.f, c1 = 0.f;
#pragma unroll
  for (int j = 0; j < 4; ++j) {
    const int c = tid * 4 + j;
    s  += xv[j];
    ss += xv[j] * xv[j];
    a0 += xv[j] * wg[c * 2];
    a1 += xv[j] * wg[c * 2 + 1];
    c0 += xv[j] * wn[c * 2];
    c1 += xv[j] * wn[c * 2 + 1];
  }

  {
    bf16x4 o;
#pragma unroll
    for (int j = 0; j < 4; ++j) o[j] = (bf16)xv[j];
    *(bf16x4*)(x_bf + (size_t)row * MM + tid * 4) = o;
  }

#pragma unroll
  for (int off = 32; off >= 1; off >>= 1) {
    s  += __shfl_xor(s,  off, 64);  ss += __shfl_xor(ss, off, 64);
    a0 += __shfl_xor(a0, off, 64);  a1 += __shfl_xor(a1, off, 64);
    c0 += __shfl_xor(c0, off, 64);  c1 += __shfl_xor(c1, off, 64);
  }
  __shared__ float red[24];
  const int w = tid >> 6;
  if ((tid & 63) == 0) {
    red[w * 6]     = s;  red[w * 6 + 1] = ss;
    red[w * 6 + 2] = a0; red[w * 6 + 3] = a1;
    red[w * 6 + 4] = c0; red[w * 6 + 5] = c1;
  }
  __syncthreads();
  s  = red[0] + red[6]  + red[12] + red[18];
  ss = red[1] + red[7]  + red[13] + red[19];

  const float mu   = s * (1.0f / MM);
  const float rsig = rsqrtf(ss * (1.0f / MM) - mu * mu + 1e-5f);
  const int prow = row % NQ;
#pragma unroll
  for (int j = 0; j < 4; ++j) {
    const int c = tid * 4 + j;
    const float y = (xv[j] - mu) * rsig * g[c] + bta[c];
    kv[(size_t)row * MM + c]  = (bf16)y;
    kin[(size_t)row * MM + c] = (bf16)(y + pos[(size_t)prow * MM + c]);
  }

  if (tid == 0) {
    a0 = red[2] + red[8]  + red[14] + red[20];
    a1 = red[3] + red[9]  + red[15] + red[21];
    c0 = red[4] + red[10] + red[16] + red[22];
    c1 = red[5] + red[11] + red[17] + red[23];
    const float sp0 = fmaxf(c0, 0.f) + log1pf(expf(-fabsf(c0)));
    const float sp1 = fmaxf(c1, 0.f) + log1pf(expf(-fabsf(c1)));
    const float l0 = a0 + noise[row * 2]     * (sp0 + 0.01f);
    const float l1 = a1 + noise[row * 2 + 1] * (sp1 + 0.01f);
    const float mx = fmaxf(l0, l1);
    const float e0 = expf(l0 - mx), e1 = expf(l1 - mx);
    const float inv = 1.0f / (e0 + e1);
    const float p0 = e0 * inv, p1 = e1 * inv;
    const float den = 1.0f / (p0 + p1 + 1e-6f);
    gates[row * 2]     = p0 * den;
    gates[row * 2 + 1] = p1 * den;
  }
}

__global__ __launch_bounds__(256) void ln_q_kernel(
    const float* __restrict__ query, const float* __restrict__ g,
    const float* __restrict__ bta, const float* __restrict__ pos,
    bf16* __restrict__ qout)
{
  const int row = blockIdx.x, tid = threadIdx.x;
  f32x4 xv = *(const f32x4*)(query + (size_t)row * MM + tid * 4);
  float s = 0.f, ss = 0.f;
#pragma unroll
  for (int j = 0; j < 4; ++j) { s += xv[j]; ss += xv[j] * xv[j]; }
#pragma unroll
  for (int off = 32; off >= 1; off >>= 1) { s += __shfl_xor(s, off, 64); ss += __shfl_xor(ss, off, 64); }
  __shared__ float red[8];
  const int w = tid >> 6;
  if ((tid & 63) == 0) { red[w] = s; red[4 + w] = ss; }
  __syncthreads();
  s  = red[0] + red[1] + red[2] + red[3];
  ss = red[4] + red[5] + red[6] + red[7];
  const float mu = s * (1.0f / MM);
  const float rsig = rsqrtf(ss * (1.0f / MM) - mu * mu + 1e-5f);
#pragma unroll
  for (int j = 0; j < 4; ++j) {
    const int c = tid * 4 + j;
    const float y = (xv[j] - mu) * rsig * g[c] + bta[c] + pos[(size_t)row * MM + c];
    qout[(size_t)row * MM + c] = (bf16)y;
  }
}

// ===========================================================================
extern "C" void kernel_launch(void* const* d_in, const int* in_sizes, int n_in,
                              void* d_out, int out_size, void* d_ws, size_t ws_size,
                              hipStream_t stream)
{
  const float* x       = (const float*)d_in[0];
  const float* noise   = (const float*)d_in[1];
  const float* W1      = (const float*)d_in[2];
  const float* b1      = (const float*)d_in[3];
  const float* W2      = (const float*)d_in[4];
  const float* b2      = (const float*)d_in[5];
  const float* query   = (const float*)d_in[6];
  const float* pos     = (const float*)d_in[7];
  const float* ln_q_g  = (const float*)d_in[8];
  const float* ln_q_b  = (const float*)d_in[9];
  const float* ln_kv_g = (const float*)d_in[10];
  const float* ln_kv_b = (const float*)d_in[11];
  const float* ipw     = (const float*)d_in[12];
  const float* ipb     = (const float*)d_in[13];
  const float* out_w   = (const float*)d_in[14];
  const float* out_b   = (const float*)d_in[15];
  const float* w_gate  = (const float*)d_in[16];
  const float* w_noise = (const float*)d_in[17];
  float* out = (float*)d_out;  // (16,576,4096) float32 = 150994944 B

  // Workspace layout (bytes). Attention chain runs first; the h region
  // [0, 75497472) holds kin/kp/vp/qbuf/qp/ipwb/outwb during the attention
  // phase, then h afterwards. kv and attn_out live in d_out scratch
  // (both dead before the final GB GEMM overwrites d_out).
  char* ws = (char*)d_ws;
  bf16*  kin   = (bf16*)(ws);
  bf16*  ctx   = kin;                              // after kin dead
  bf16*  kp    = (bf16*)(ws + 18874368);
  bf16*  vp    = (bf16*)(ws + 37748736);
  bf16*  qbuf  = (bf16*)(ws + 56623104);
  bf16*  qp    = (bf16*)(ws + 57802752);
  bf16*  ipwb  = (bf16*)(ws + 58982400);           // 3*1024*1024 bf16
  bf16*  outwb = (bf16*)(ws + 65273856);           // 1024*1024 bf16
  bf16*  h     = (bf16*)(ws);                      // after attention phase
  bf16*  x_bf  = (bf16*)(ws + 75497472);
  bf16*  W1b   = (bf16*)(ws + 94371840);
  bf16*  W2b   = (bf16*)(ws + 102760448);
  float* gates = (float*)(ws + 136314880);
  bf16*  kv       = (bf16*)d_out;                      // scratch, 18.9MB
  bf16*  attn_out = (bf16*)((char*)d_out + 18874368);  // scratch, 18.9MB

  // 1) weight converts + fused x pass (LN + x_bf + gating)
  cvt_kernel<<<4096,  256, 0, stream>>>(W1, W1b);    // 4096*1024
  cvt_kernel<<<16384, 256, 0, stream>>>(W2, W2b);    // 4096*4096
  cvt_kernel<<<3072,  256, 0, stream>>>(ipw,   ipwb);
  cvt_kernel<<<1024,  256, 0, stream>>>(out_w, outwb);
  lnx_kernel<<<ROWS, 256, 0, stream>>>(x, ln_kv_g, ln_kv_b, pos,
                                       w_gate, w_noise, noise,
                                       kv, kin, x_bf, gates);
  ln_q_kernel<<<NQ, 256, 0, stream>>>(query, ln_q_g, ln_q_b, pos, qbuf);

  // 2) attention chain
  gemm_bt<MODE_BIAS, bf16><<<dim3(8, 5),  256, 0, stream>>>(qbuf, ipwb, ipb, qp, nullptr, NQ, MM, MM);
  gemm_bt<MODE_BIAS, bf16><<<dim3(8, 72), 256, 0, stream>>>(kin, ipwb + (size_t)MM * MM, ipb + MM, kp, nullptr, ROWS, MM, MM);
  gemm_bt<MODE_BIAS, bf16><<<dim3(8, 72), 256, 0, stream>>>(kv, ipwb + (size_t)2 * MM * MM, ipb + 2 * MM, vp, nullptr, ROWS, MM, MM);

  attn_kernel<<<dim3(9, BATCH, HEADS), 256, 0, stream>>>(qp, kp, vp, ctx);

  gemm_bt<MODE_BIAS, bf16><<<dim3(8, 72), 256, 0, stream>>>(ctx, outwb, out_b, attn_out, nullptr, ROWS, MM, MM);

  // 3) combined expert branch:
  //    h  = g0 * gelu(x@W1^T + b1)
  //    h += g1 * gelu(attn_out@W1^T + b1)
  //    out = h @ W2^T + (g0+g1)*b2        (single big W2 GEMM)
  gemm_bt<MODE_GG,    bf16><<<dim3(32, 72), 256, 0, stream>>>(x_bf,     W1b, b1, h, gates, ROWS, HID, MM);
  gemm_bt<MODE_GGACC, bf16><<<dim3(32, 72), 256, 0, stream>>>(attn_out, W1b, b1, h, gates, ROWS, HID, MM);
  gemm_bt<MODE_GB,   float><<<dim3(32, 72), 256, 0, stream>>>(h,        W2b, b2, out, gates, ROWS, HID, HID);
}